// Round 4
// baseline (473.133 us; speedup 1.0000x reference)
//
#include <hip/hip_runtime.h>

#define NB 8
#define LSEQ 4096
#define INS 256
#define MD 4
#define ORD 256
#define HID 512
#define MSZ 1280
#define FS 4128   // complex stride for spectrum rows (2*FS = 8256 floats)
#define NSPEC 8256

// padded LDS index for FFT kernels: +1 float2 per 8
#define PD(n) ((n) + ((n) >> 3))
#define LDSN 4608

typedef __attribute__((ext_vector_type(8))) short short8;
typedef __attribute__((ext_vector_type(4))) float floatx4;

struct ush4 { unsigned short x, y, z, w; };

__device__ __forceinline__ unsigned short f2bf(float f) {
    unsigned u = __float_as_uint(f);
    u += 0x7FFF + ((u >> 16) & 1);
    return (unsigned short)(u >> 16);
}
__device__ __forceinline__ ush4 pack4(float4 v) {
    ush4 p; p.x = f2bf(v.x); p.y = f2bf(v.y); p.z = f2bf(v.z); p.w = f2bf(v.w); return p;
}

// ---------------- complex helpers ----------------
__device__ __forceinline__ float2 cmul(float2 a, float2 b) {
    return make_float2(fmaf(a.x, b.x, -(a.y * b.y)), fmaf(a.x, b.y, a.y * b.x));
}
__device__ __forceinline__ float2 cadd(float2 a, float2 b) { return make_float2(a.x + b.x, a.y + b.y); }
__device__ __forceinline__ float2 csub(float2 a, float2 b) { return make_float2(a.x - b.x, a.y - b.y); }

template <int DIR>
__device__ __forceinline__ float2 jmul(float2 z) {
    return (DIR < 0) ? make_float2(z.y, -z.x) : make_float2(-z.y, z.x);
}

// In-place Stockham DIF radix-8 stage on padded buffer. 512 threads.
template <int DIR, int N_, int S_>
__device__ __forceinline__ void fft_stage_ip(float2* __restrict__ X, int tid) {
    constexpr int M_ = N_ / 8;
    const int q = tid & (S_ - 1);
    const int p = tid / S_;
    const int rb = q + S_ * p;
    const float2 a0 = X[PD(rb + S_ * 0 * M_)];
    const float2 a1 = X[PD(rb + S_ * 1 * M_)];
    const float2 a2 = X[PD(rb + S_ * 2 * M_)];
    const float2 a3 = X[PD(rb + S_ * 3 * M_)];
    const float2 a4 = X[PD(rb + S_ * 4 * M_)];
    const float2 a5 = X[PD(rb + S_ * 5 * M_)];
    const float2 a6 = X[PD(rb + S_ * 6 * M_)];
    const float2 a7 = X[PD(rb + S_ * 7 * M_)];

    const float2 e0 = cadd(a0, a4), e1 = csub(a0, a4);
    const float2 e2 = cadd(a2, a6), e3 = jmul<DIR>(csub(a2, a6));
    const float2 E0 = cadd(e0, e2), E2 = csub(e0, e2);
    const float2 E1 = cadd(e1, e3), E3 = csub(e1, e3);
    const float2 f0 = cadd(a1, a5), f1 = csub(a1, a5);
    const float2 f2 = cadd(a3, a7), f3 = jmul<DIR>(csub(a3, a7));
    const float2 O0 = cadd(f0, f2), O2 = csub(f0, f2);
    const float2 O1 = cadd(f1, f3), O3 = csub(f1, f3);

    constexpr float C707 = 0.70710678118654752440f;
    const float2 W1 = make_float2(C707, DIR * C707);
    const float2 W3 = make_float2(-C707, DIR * C707);
    const float2 T1 = cmul(O1, W1);
    const float2 T2 = jmul<DIR>(O2);
    const float2 T3 = cmul(O3, W3);

    const float2 b0 = cadd(E0, O0), b4 = csub(E0, O0);
    const float2 b1 = cadd(E1, T1), b5 = csub(E1, T1);
    const float2 b2 = cadd(E2, T2), b6 = csub(E2, T2);
    const float2 b3 = cadd(E3, T3), b7 = csub(E3, T3);

    float sn, cs;
    __sincosf((DIR * 6.2831853071795864769f / (float)N_) * (float)p, &sn, &cs);
    const float2 w1 = make_float2(cs, sn);

    __syncthreads();

    const int wb = q + S_ * 8 * p;
    X[PD(wb + 0 * S_)] = b0;
    float2 w = w1;
    X[PD(wb + 1 * S_)] = cmul(b1, w); w = cmul(w, w1);
    X[PD(wb + 2 * S_)] = cmul(b2, w); w = cmul(w, w1);
    X[PD(wb + 3 * S_)] = cmul(b3, w); w = cmul(w, w1);
    X[PD(wb + 4 * S_)] = cmul(b4, w); w = cmul(w, w1);
    X[PD(wb + 5 * S_)] = cmul(b5, w); w = cmul(w, w1);
    X[PD(wb + 6 * S_)] = cmul(b6, w); w = cmul(w, w1);
    X[PD(wb + 7 * S_)] = cmul(b7, w);
    __syncthreads();
}

template <int DIR>
__device__ __forceinline__ void fft4096_ip(float2* A, int tid) {
    __syncthreads();
    fft_stage_ip<DIR, 4096, 1>(A, tid);
    fft_stage_ip<DIR, 512, 8>(A, tid);
    fft_stage_ip<DIR, 64, 64>(A, tid);
    fft_stage_ip<DIR, 8, 512>(A, tid);
}

// ---------------- K1: u = relu(x @ Wu_w^T + Wu_b), stored transposed u_t[(b*4+d)][t] ----------------
extern "C" __global__ __launch_bounds__(256) void u_relu_k(
    const float* __restrict__ x, const float* __restrict__ Wuw,
    const float* __restrict__ Wub, float* __restrict__ u_t) {
    const int gid = blockIdx.x * 256 + threadIdx.x;
    const int row = gid >> 6;
    const int lane = threadIdx.x & 63;
    const float4 xv = ((const float4*)x)[(size_t)row * 64 + lane];
    const float4 w0 = ((const float4*)Wuw)[0 * 64 + lane];
    const float4 w1 = ((const float4*)Wuw)[1 * 64 + lane];
    const float4 w2 = ((const float4*)Wuw)[2 * 64 + lane];
    const float4 w3 = ((const float4*)Wuw)[3 * 64 + lane];
    float a0 = xv.x * w0.x + xv.y * w0.y + xv.z * w0.z + xv.w * w0.w;
    float a1 = xv.x * w1.x + xv.y * w1.y + xv.z * w1.z + xv.w * w1.w;
    float a2 = xv.x * w2.x + xv.y * w2.y + xv.z * w2.z + xv.w * w2.w;
    float a3 = xv.x * w3.x + xv.y * w3.y + xv.z * w3.z + xv.w * w3.w;
#pragma unroll
    for (int off = 1; off < 64; off <<= 1) {
        a0 += __shfl_xor(a0, off);
        a1 += __shfl_xor(a1, off);
        a2 += __shfl_xor(a2, off);
        a3 += __shfl_xor(a3, off);
    }
    if (lane < 4) {
        float v = (lane == 0) ? a0 : (lane == 1) ? a1 : (lane == 2) ? a2 : a3;
        v = fmaxf(v + Wub[lane], 0.0f);
        const int b = row >> 12, t = row & 4095;
        u_t[((size_t)(b * 4 + lane)) * LSEQ + t] = v;
    }
}

// ---------------- K2/K3: rfft of real rows (len 4096, zero-padded to 8192) -> 4097 bins ----------------
extern "C" __global__ __launch_bounds__(512) void rfft_rows_k(
    const float* __restrict__ in, float2* __restrict__ out) {
    __shared__ float2 A[LDSN];
    const int row = blockIdx.x;
    const int tid = threadIdx.x;
    const float2* rp = (const float2*)(in + (size_t)row * LSEQ);
#pragma unroll
    for (int j = 0; j < 8; ++j) {
        const int n = tid + j * 512;
        A[PD(n)] = (n < 2048) ? rp[n] : make_float2(0.f, 0.f);
    }
    fft4096_ip<-1>(A, tid);
    float2* op = out + (size_t)row * FS;
#pragma unroll
    for (int j = 0; j < 9; ++j) {
        const int k = tid + j * 512;
        if (k <= 4096) {
            const float2 Zk = A[PD(k & 4095)];
            const float2 Zm = A[PD((4096 - k) & 4095)];
            const float2 E = make_float2(0.5f * (Zk.x + Zm.x), 0.5f * (Zk.y - Zm.y));
            const float2 D = make_float2(0.5f * (Zk.x - Zm.x), 0.5f * (Zk.y + Zm.y));
            const float2 O = make_float2(D.y, -D.x);
            float sn, cs;
            __sincosf(-7.66990393942820614e-4f * (float)k, &sn, &cs);
            op[k] = cadd(E, cmul(make_float2(cs, sn), O));
        }
    }
}

// ---------------- K3b: transpose fftH [256 o][8256 s] fp32 -> fftHT [8256 s][256 o] bf16 ----------------
extern "C" __global__ __launch_bounds__(256) void ht_k(
    const float* __restrict__ fftH, unsigned short* __restrict__ fftHT) {
    __shared__ float T[64 * 65];
    const int tid = threadIdx.x;
    const int s0 = blockIdx.x * 64;  // 129 blocks
    const int o0 = blockIdx.y * 64;  // 4 blocks
    const int r = tid >> 4, c4 = (tid & 15) * 4;
#pragma unroll
    for (int i = 0; i < 4; ++i) {
        const int o = r + 16 * i;
        const float4 v = *(const float4*)(fftH + (size_t)(o0 + o) * NSPEC + s0 + c4);
        *(float4*)(&T[o * 65 + c4]) = v;
    }
    __syncthreads();
#pragma unroll
    for (int i = 0; i < 4; ++i) {
        const int s = r + 16 * i;
        ush4 p;
        p.x = f2bf(T[(c4 + 0) * 65 + s]);
        p.y = f2bf(T[(c4 + 1) * 65 + s]);
        p.z = f2bf(T[(c4 + 2) * 65 + s]);
        p.w = f2bf(T[(c4 + 3) * 65 + s]);
        *(ush4*)(&fftHT[(size_t)(s0 + s) * 256 + o0 + c4]) = p;
    }
}

// ---------------- K4: fftG[m=h*4+d][n] = sum_o Whw[h, d*256+o] * fftHT[n][o]  (bf16 MFMA) ----------------
extern "C" __global__ __launch_bounds__(256) void g_gemm_k(
    const float* __restrict__ Whw, const unsigned short* __restrict__ fftHT,
    float* __restrict__ fftG) {
    __shared__ __align__(16) char smem[36864];
    short* As = (short*)smem;             // [128][72]
    short* Bs = (short*)(smem + 18432);   // [128][72]
    float* Ct = (float*)smem;             // epilogue reuse: [128][68] fp32 = 34816 B

    const int tid = threadIdx.x, lane = tid & 63, wave = tid >> 6;
    const int n0 = blockIdx.x * 128;  // 65 tiles, last partial (64 valid)
    const int m0 = blockIdx.y * 128;  // 16 tiles over 2048 rows (m = h*4+d)
    floatx4 acc[2][8];
#pragma unroll
    for (int i = 0; i < 2; ++i)
#pragma unroll
        for (int j = 0; j < 8; ++j) acc[i][j] = (floatx4){0.f, 0.f, 0.f, 0.f};

    const int sr = tid >> 4, sc = (tid & 15) * 4;
    for (int kc = 0; kc < 4; ++kc) {
#pragma unroll
        for (int i = 0; i < 8; ++i) {
            const int row = sr + 16 * i;
            const int m = m0 + row;
            const float4 av = *(const float4*)(Whw + (size_t)(m >> 2) * MSZ + (m & 3) * 256 + kc * 64 + sc);
            *(ush4*)(&As[row * 72 + sc]) = pack4(av);
            const int n = n0 + row;
            ush4 bv;
            if (n < NSPEC) bv = *(const ush4*)(fftHT + (size_t)n * 256 + kc * 64 + sc);
            else { bv.x = bv.y = bv.z = bv.w = 0; }
            *(ush4*)(&Bs[row * 72 + sc]) = bv;
        }
        __syncthreads();
        const int arow = (wave * 32 + (lane & 15)) * 72;
        const int brow = (lane & 15) * 72;
        const int kq = 8 * (lane >> 4);
#pragma unroll
        for (int kk = 0; kk < 2; ++kk) {
            const int ko = kk * 32 + kq;
            const short8 a0 = *(const short8*)(&As[arow + ko]);
            const short8 a1 = *(const short8*)(&As[arow + 16 * 72 + ko]);
#pragma unroll
            for (int nf = 0; nf < 8; ++nf) {
                const short8 bv = *(const short8*)(&Bs[brow + nf * 16 * 72 + ko]);
                acc[0][nf] = __builtin_amdgcn_mfma_f32_16x16x32_bf16(a0, bv, acc[0][nf], 0, 0, 0);
                acc[1][nf] = __builtin_amdgcn_mfma_f32_16x16x32_bf16(a1, bv, acc[1][nf], 0, 0, 0);
            }
        }
        __syncthreads();
    }
    // epilogue: transpose C through LDS, store float4-coalesced (full 128B lines)
    const int wm = wave * 32;
#pragma unroll 1
    for (int half = 0; half < 2; ++half) {
        __syncthreads();
#pragma unroll
        for (int nfl = 0; nfl < 4; ++nfl) {
            const int nf = half * 4 + nfl;
            const int nloc = nfl * 16 + (lane & 15);
#pragma unroll
            for (int mf = 0; mf < 2; ++mf)
#pragma unroll
                for (int r = 0; r < 4; ++r) {
                    const int row = wm + mf * 16 + 4 * (lane >> 4) + r;
                    Ct[row * 68 + nloc] = acc[mf][nf][r];
                }
        }
        __syncthreads();
#pragma unroll
        for (int i = 0; i < 8; ++i) {
            const int idx = tid + i * 256;
            const int row = idx >> 4, f4 = idx & 15;
            const int n = n0 + half * 64 + f4 * 4;
            if (n < NSPEC) {
                const float4 v = *(const float4*)&Ct[row * 68 + f4 * 4];
                *(float4*)&fftG[(size_t)(m0 + row) * NSPEC + n] = v;
            }
        }
    }
}

// ---------------- K5: S = sum_d fftU[b,d] * fftG[h,d]; y[b,h,:] = irfft(S)[0:4096] ----------------
extern "C" __global__ __launch_bounds__(512) void conv_ifft_k(
    const float2* __restrict__ fftU, const float2* __restrict__ fftG, float* __restrict__ y) {
    __shared__ float2 A[LDSN];
    __shared__ float2 S4096;
    const int h = blockIdx.x >> 3;
    const int b = blockIdx.x & 7;
    const int tid = threadIdx.x;
    const float2* U = fftU + (size_t)b * MD * FS;
    const float2* G = fftG + (size_t)h * MD * FS;
#pragma unroll
    for (int j = 0; j < 9; ++j) {
        const int k = tid + j * 512;
        if (k <= 4096) {
            float2 s = make_float2(0.f, 0.f);
#pragma unroll
            for (int d = 0; d < MD; ++d) {
                const float2 uu = U[d * FS + k];
                const float2 gg = G[d * FS + k];
                s.x = fmaf(uu.x, gg.x, fmaf(-uu.y, gg.y, s.x));
                s.y = fmaf(uu.x, gg.y, fmaf(uu.y, gg.x, s.y));
            }
            if (k < 4096) A[PD(k)] = s;
            else S4096 = s;
        }
    }
    __syncthreads();
    float2 Sk[8], Sm[8];
#pragma unroll
    for (int j = 0; j < 8; ++j) {
        const int k = tid + j * 512;
        Sk[j] = A[PD(k)];
        Sm[j] = (k == 0) ? S4096 : A[PD(4096 - k)];
    }
    __syncthreads();
#pragma unroll
    for (int j = 0; j < 8; ++j) {
        const int k = tid + j * 512;
        const float2 E = make_float2(0.5f * (Sk[j].x + Sm[j].x), 0.5f * (Sk[j].y - Sm[j].y));
        const float2 D = make_float2(0.5f * (Sk[j].x - Sm[j].x), 0.5f * (Sk[j].y + Sm[j].y));
        float sn, cs;
        __sincosf(7.66990393942820614e-4f * (float)k, &sn, &cs);
        const float2 O = cmul(D, make_float2(cs, sn));
        A[PD(k)] = make_float2(E.x - O.y, E.y + O.x);
    }
    fft4096_ip<1>(A, tid);
    float2* yp = (float2*)(y + ((size_t)(b * HID + h)) * LSEQ);
    const float inv = 1.0f / 4096.0f;
#pragma unroll
    for (int j = 0; j < 4; ++j) {
        const int n = tid + j * 512;
        const float2 z = A[PD(n)];
        yp[n] = make_float2(z.x * inv, z.y * inv);
    }
}

// ---------------- K6: h = relu(x @ Whw_x^T + y^T + bias) via bf16 MFMA; also h_last ----------------
extern "C" __global__ __launch_bounds__(256) void out_gemm_k(
    const float* __restrict__ x, const float* __restrict__ Whw, const float* __restrict__ Whb,
    const float* __restrict__ y, float* __restrict__ out) {
    __shared__ __align__(16) char smem[36864];
    short* As = (short*)smem;             // [128][72]
    short* Bs = (short*)(smem + 18432);   // [128][72]
    float* Ys = (float*)smem;             // epilogue: [64][132] staging = 33792 B (aliased, barrier-separated)
    float* Ct = (float*)smem;             // epilogue: [128][68] transposed result = 34816 B

    const int tid = threadIdx.x, lane = tid & 63, wave = tid >> 6;
    const int m0 = blockIdx.x * 128;  // global row (b*4096 + t)
    const int h0 = blockIdx.y * 128;
    const int b = m0 >> 12;
    const int t0 = m0 & 4095;

    floatx4 acc[2][8];
#pragma unroll
    for (int i = 0; i < 2; ++i)
#pragma unroll
        for (int j = 0; j < 8; ++j) acc[i][j] = (floatx4){0.f, 0.f, 0.f, 0.f};

    const int sr = tid >> 4, sc = (tid & 15) * 4;
    const float* Axp = x + (size_t)(m0 + sr) * INS + sc;
    const float* Bxp = Whw + (size_t)(h0 + sr) * MSZ + 1024 + sc;

    for (int kc = 0; kc < 4; ++kc) {
#pragma unroll
        for (int i = 0; i < 8; ++i) {
            const int row = sr + 16 * i;
            const float4 av = *(const float4*)(Axp + (size_t)(16 * i) * INS + kc * 64);
            *(ush4*)(&As[row * 72 + sc]) = pack4(av);
            const float4 bv = *(const float4*)(Bxp + (size_t)(16 * i) * MSZ + kc * 64);
            *(ush4*)(&Bs[row * 72 + sc]) = pack4(bv);
        }
        __syncthreads();
        const int arow = (wave * 32 + (lane & 15)) * 72;
        const int brow = (lane & 15) * 72;
        const int kq = 8 * (lane >> 4);
#pragma unroll
        for (int kk = 0; kk < 2; ++kk) {
            const int ko = kk * 32 + kq;
            const short8 a0 = *(const short8*)(&As[arow + ko]);
            const short8 a1 = *(const short8*)(&As[arow + 16 * 72 + ko]);
#pragma unroll
            for (int nf = 0; nf < 8; ++nf) {
                const short8 bv = *(const short8*)(&Bs[brow + nf * 16 * 72 + ko]);
                acc[0][nf] = __builtin_amdgcn_mfma_f32_16x16x32_bf16(a0, bv, acc[0][nf], 0, 0, 0);
                acc[1][nf] = __builtin_amdgcn_mfma_f32_16x16x32_bf16(a1, bv, acc[1][nf], 0, 0, 0);
            }
        }
        __syncthreads();
    }

    // epilogue per 64-h half: stage y^T -> compute relu(acc+y+bias) in regs
    // -> transpose via LDS -> float4-coalesced stores (full 128B lines)
    const int wm = wave * 32;
    const int yr = tid >> 5, yc = (tid & 31) * 4;
#pragma unroll 1
    for (int half = 0; half < 2; ++half) {
        __syncthreads();
#pragma unroll
        for (int i = 0; i < 8; ++i) {
            const int hh = yr + 8 * i;
            const float4 v = *(const float4*)(y + ((size_t)(b * HID + h0 + half * 64 + hh)) * LSEQ + t0 + yc);
            *(float4*)(&Ys[hh * 132 + yc]) = v;
        }
        __syncthreads();
        float v[4][2][4];
#pragma unroll
        for (int nfl = 0; nfl < 4; ++nfl) {
            const int nf = half * 4 + nfl;
            const int hh = nfl * 16 + (lane & 15);
            const float bias = Whb[h0 + half * 64 + hh];
#pragma unroll
            for (int mf = 0; mf < 2; ++mf)
#pragma unroll
                for (int r = 0; r < 4; ++r) {
                    const int row = wm + mf * 16 + 4 * (lane >> 4) + r;
                    v[nfl][mf][r] = fmaxf(acc[mf][nf][r] + Ys[hh * 132 + row] + bias, 0.f);
                }
        }
        __syncthreads();
#pragma unroll
        for (int nfl = 0; nfl < 4; ++nfl) {
            const int nloc = nfl * 16 + (lane & 15);
#pragma unroll
            for (int mf = 0; mf < 2; ++mf)
#pragma unroll
                for (int r = 0; r < 4; ++r) {
                    const int row = wm + mf * 16 + 4 * (lane >> 4) + r;
                    Ct[row * 68 + nloc] = v[nfl][mf][r];
                }
        }
        __syncthreads();
#pragma unroll
        for (int i = 0; i < 8; ++i) {
            const int idx = tid + i * 256;
            const int row = idx >> 4, f4 = idx & 15;
            const float4 t = *(const float4*)&Ct[row * 68 + f4 * 4];
            *(float4*)(out + (size_t)(m0 + row) * HID + h0 + half * 64 + f4 * 4) = t;
            if (((m0 + row) & 4095) == 4095)
                *(float4*)(out + (size_t)NB * LSEQ * HID + (size_t)b * HID + h0 + half * 64 + f4 * 4) = t;
        }
    }
}

extern "C" void kernel_launch(void* const* d_in, const int* in_sizes, int n_in,
                              void* d_out, int out_size, void* d_ws, size_t ws_size,
                              hipStream_t stream) {
    const float* x   = (const float*)d_in[0];
    const float* Wuw = (const float*)d_in[1];
    const float* Wub = (const float*)d_in[2];
    const float* Whw = (const float*)d_in[3];
    const float* Whb = (const float*)d_in[4];
    const float* H   = (const float*)d_in[5];
    float* ws = (float*)d_ws;
    // workspace layout (floats)
    float* fftG = ws;                        // 2048*8256      = 16,908,288
    float* yb   = ws + 16908288;             // 8*512*4096     = 16,777,216
    float* fftU = ws + 33685504;             // 32*FS*2        =    264,192
    float* fftH = ws + 33949696;             // 256*FS*2       =  2,113,536
    float* ut   = ws + 36063232;             // 32*4096        =    131,072
    unsigned short* fftHT = (unsigned short*)(ws + 36194304);  // 8256*256 bf16
    float* out  = (float*)d_out;

    hipLaunchKernelGGL(u_relu_k, dim3(8192), dim3(256), 0, stream, x, Wuw, Wub, ut);
    hipLaunchKernelGGL(rfft_rows_k, dim3(32), dim3(512), 0, stream, ut, (float2*)fftU);
    hipLaunchKernelGGL(rfft_rows_k, dim3(256), dim3(512), 0, stream, H, (float2*)fftH);
    hipLaunchKernelGGL(ht_k, dim3(129, 4), dim3(256), 0, stream, fftH, fftHT);
    hipLaunchKernelGGL(g_gemm_k, dim3(65, 16), dim3(256), 0, stream, Whw, fftHT, fftG);
    hipLaunchKernelGGL(conv_ifft_k, dim3(4096), dim3(512), 0, stream,
                       (const float2*)fftU, (const float2*)fftG, yb);
    hipLaunchKernelGGL(out_gemm_k, dim3(256, 4), dim3(256), 0, stream, x, Whw, Whb, yb, out);
}

// Round 6
// 443.480 us; speedup vs baseline: 1.0669x; 1.0669x over previous
//
#include <hip/hip_runtime.h>

#define NB 8
#define LSEQ 4096
#define INS 256
#define MD 4
#define ORD 256
#define HID 512
#define MSZ 1280
#define FS 4128   // complex stride for spectrum rows (2*FS = 8256 floats)
#define NSPEC 8256

// padded LDS index for FFT kernels: +1 float2 per 8
#define PD(n) ((n) + ((n) >> 3))
#define LDSN 4608

typedef __attribute__((ext_vector_type(8))) short short8;
typedef __attribute__((ext_vector_type(4))) float floatx4;

struct ush4 { unsigned short x, y, z, w; };

__device__ __forceinline__ unsigned short f2bf(float f) {
    unsigned u = __float_as_uint(f);
    u += 0x7FFF + ((u >> 16) & 1);
    return (unsigned short)(u >> 16);
}
__device__ __forceinline__ ush4 pack4(float4 v) {
    ush4 p; p.x = f2bf(v.x); p.y = f2bf(v.y); p.z = f2bf(v.z); p.w = f2bf(v.w); return p;
}
__device__ __forceinline__ float bf2f(unsigned short s) {
    return __uint_as_float(((unsigned)s) << 16);
}

// ---------------- complex helpers ----------------
__device__ __forceinline__ float2 cmul(float2 a, float2 b) {
    return make_float2(fmaf(a.x, b.x, -(a.y * b.y)), fmaf(a.x, b.y, a.y * b.x));
}
__device__ __forceinline__ float2 cadd(float2 a, float2 b) { return make_float2(a.x + b.x, a.y + b.y); }
__device__ __forceinline__ float2 csub(float2 a, float2 b) { return make_float2(a.x - b.x, a.y - b.y); }

template <int DIR>
__device__ __forceinline__ float2 jmul(float2 z) {
    return (DIR < 0) ? make_float2(z.y, -z.x) : make_float2(-z.y, z.x);
}

// In-place Stockham DIF radix-8 stage on padded buffer. 512 threads.
template <int DIR, int N_, int S_>
__device__ __forceinline__ void fft_stage_ip(float2* __restrict__ X, int tid) {
    constexpr int M_ = N_ / 8;
    const int q = tid & (S_ - 1);
    const int p = tid / S_;
    const int rb = q + S_ * p;
    const float2 a0 = X[PD(rb + S_ * 0 * M_)];
    const float2 a1 = X[PD(rb + S_ * 1 * M_)];
    const float2 a2 = X[PD(rb + S_ * 2 * M_)];
    const float2 a3 = X[PD(rb + S_ * 3 * M_)];
    const float2 a4 = X[PD(rb + S_ * 4 * M_)];
    const float2 a5 = X[PD(rb + S_ * 5 * M_)];
    const float2 a6 = X[PD(rb + S_ * 6 * M_)];
    const float2 a7 = X[PD(rb + S_ * 7 * M_)];

    const float2 e0 = cadd(a0, a4), e1 = csub(a0, a4);
    const float2 e2 = cadd(a2, a6), e3 = jmul<DIR>(csub(a2, a6));
    const float2 E0 = cadd(e0, e2), E2 = csub(e0, e2);
    const float2 E1 = cadd(e1, e3), E3 = csub(e1, e3);
    const float2 f0 = cadd(a1, a5), f1 = csub(a1, a5);
    const float2 f2 = cadd(a3, a7), f3 = jmul<DIR>(csub(a3, a7));
    const float2 O0 = cadd(f0, f2), O2 = csub(f0, f2);
    const float2 O1 = cadd(f1, f3), O3 = csub(f1, f3);

    constexpr float C707 = 0.70710678118654752440f;
    const float2 W1 = make_float2(C707, DIR * C707);
    const float2 W3 = make_float2(-C707, DIR * C707);
    const float2 T1 = cmul(O1, W1);
    const float2 T2 = jmul<DIR>(O2);
    const float2 T3 = cmul(O3, W3);

    const float2 b0 = cadd(E0, O0), b4 = csub(E0, O0);
    const float2 b1 = cadd(E1, T1), b5 = csub(E1, T1);
    const float2 b2 = cadd(E2, T2), b6 = csub(E2, T2);
    const float2 b3 = cadd(E3, T3), b7 = csub(E3, T3);

    float sn, cs;
    __sincosf((DIR * 6.2831853071795864769f / (float)N_) * (float)p, &sn, &cs);
    const float2 w1 = make_float2(cs, sn);

    __syncthreads();

    const int wb = q + S_ * 8 * p;
    X[PD(wb + 0 * S_)] = b0;
    float2 w = w1;
    X[PD(wb + 1 * S_)] = cmul(b1, w); w = cmul(w, w1);
    X[PD(wb + 2 * S_)] = cmul(b2, w); w = cmul(w, w1);
    X[PD(wb + 3 * S_)] = cmul(b3, w); w = cmul(w, w1);
    X[PD(wb + 4 * S_)] = cmul(b4, w); w = cmul(w, w1);
    X[PD(wb + 5 * S_)] = cmul(b5, w); w = cmul(w, w1);
    X[PD(wb + 6 * S_)] = cmul(b6, w); w = cmul(w, w1);
    X[PD(wb + 7 * S_)] = cmul(b7, w);
    __syncthreads();
}

template <int DIR>
__device__ __forceinline__ void fft4096_ip(float2* A, int tid) {
    __syncthreads();
    fft_stage_ip<DIR, 4096, 1>(A, tid);
    fft_stage_ip<DIR, 512, 8>(A, tid);
    fft_stage_ip<DIR, 64, 64>(A, tid);
    fft_stage_ip<DIR, 8, 512>(A, tid);
}

// ---------------- K1: u = relu(x @ Wu_w^T + Wu_b), stored transposed u_t[(b*4+d)][t] ----------------
extern "C" __global__ __launch_bounds__(256) void u_relu_k(
    const float* __restrict__ x, const float* __restrict__ Wuw,
    const float* __restrict__ Wub, float* __restrict__ u_t) {
    const int gid = blockIdx.x * 256 + threadIdx.x;
    const int row = gid >> 6;
    const int lane = threadIdx.x & 63;
    const float4 xv = ((const float4*)x)[(size_t)row * 64 + lane];
    const float4 w0 = ((const float4*)Wuw)[0 * 64 + lane];
    const float4 w1 = ((const float4*)Wuw)[1 * 64 + lane];
    const float4 w2 = ((const float4*)Wuw)[2 * 64 + lane];
    const float4 w3 = ((const float4*)Wuw)[3 * 64 + lane];
    float a0 = xv.x * w0.x + xv.y * w0.y + xv.z * w0.z + xv.w * w0.w;
    float a1 = xv.x * w1.x + xv.y * w1.y + xv.z * w1.z + xv.w * w1.w;
    float a2 = xv.x * w2.x + xv.y * w2.y + xv.z * w2.z + xv.w * w2.w;
    float a3 = xv.x * w3.x + xv.y * w3.y + xv.z * w3.z + xv.w * w3.w;
#pragma unroll
    for (int off = 1; off < 64; off <<= 1) {
        a0 += __shfl_xor(a0, off);
        a1 += __shfl_xor(a1, off);
        a2 += __shfl_xor(a2, off);
        a3 += __shfl_xor(a3, off);
    }
    if (lane < 4) {
        float v = (lane == 0) ? a0 : (lane == 1) ? a1 : (lane == 2) ? a2 : a3;
        v = fmaxf(v + Wub[lane], 0.0f);
        const int b = row >> 12, t = row & 4095;
        u_t[((size_t)(b * 4 + lane)) * LSEQ + t] = v;
    }
}

// ---------------- K2: rfft of u rows (len 4096, zero-padded to 8192) -> fp32 spectrum ----------------
extern "C" __global__ __launch_bounds__(512) void rfft_u_k(
    const float* __restrict__ in, float2* __restrict__ out) {
    __shared__ float2 A[LDSN];
    const int row = blockIdx.x;
    const int tid = threadIdx.x;
    const float2* rp = (const float2*)(in + (size_t)row * LSEQ);
#pragma unroll
    for (int j = 0; j < 8; ++j) {
        const int n = tid + j * 512;
        A[PD(n)] = (n < 2048) ? rp[n] : make_float2(0.f, 0.f);
    }
    fft4096_ip<-1>(A, tid);
    float2* op = out + (size_t)row * FS;
#pragma unroll
    for (int j = 0; j < 9; ++j) {
        const int k = tid + j * 512;
        if (k <= 4096) {
            const float2 Zk = A[PD(k & 4095)];
            const float2 Zm = A[PD((4096 - k) & 4095)];
            const float2 E = make_float2(0.5f * (Zk.x + Zm.x), 0.5f * (Zk.y - Zm.y));
            const float2 D = make_float2(0.5f * (Zk.x - Zm.x), 0.5f * (Zk.y + Zm.y));
            const float2 O = make_float2(D.y, -D.x);
            float sn, cs;
            __sincosf(-7.66990393942820614e-4f * (float)k, &sn, &cs);
            op[k] = cadd(E, cmul(make_float2(cs, sn), O));
        }
    }
}

// ---------------- K3: rfft of H rows -> bf16 TRANSPOSED fftHT[s][o] (s = float index 0..8255) ----------------
extern "C" __global__ __launch_bounds__(512) void rfft_ht_k(
    const float* __restrict__ in, unsigned short* __restrict__ fftHT) {
    __shared__ float2 A[LDSN];
    const int o = blockIdx.x;  // 0..255
    const int tid = threadIdx.x;
    const float2* rp = (const float2*)(in + (size_t)o * LSEQ);
#pragma unroll
    for (int j = 0; j < 8; ++j) {
        const int n = tid + j * 512;
        A[PD(n)] = (n < 2048) ? rp[n] : make_float2(0.f, 0.f);
    }
    fft4096_ip<-1>(A, tid);
#pragma unroll
    for (int j = 0; j < 9; ++j) {
        const int k = tid + j * 512;
        if (k <= 4096) {
            const float2 Zk = A[PD(k & 4095)];
            const float2 Zm = A[PD((4096 - k) & 4095)];
            const float2 E = make_float2(0.5f * (Zk.x + Zm.x), 0.5f * (Zk.y - Zm.y));
            const float2 D = make_float2(0.5f * (Zk.x - Zm.x), 0.5f * (Zk.y + Zm.y));
            const float2 O = make_float2(D.y, -D.x);
            float sn, cs;
            __sincosf(-7.66990393942820614e-4f * (float)k, &sn, &cs);
            const float2 c = cadd(E, cmul(make_float2(cs, sn), O));
            fftHT[(size_t)(2 * k + 0) * 256 + o] = f2bf(c.x);
            fftHT[(size_t)(2 * k + 1) * 256 + o] = f2bf(c.y);
        }
    }
    // zero the tail rows (n = 8194..8255) so g_gemm never reads poisoned bf16
    for (int n = 8194 + tid; n < NSPEC; n += 512) fftHT[(size_t)n * 256 + o] = 0;
}

// ---------------- K4: fftG[m=h*4+d][n] = sum_o Whw[h, d*256+o] * fftHT[n][o]  (bf16 MFMA, bf16 out) ----------------
extern "C" __global__ __launch_bounds__(256) void g_gemm_k(
    const float* __restrict__ Whw, const unsigned short* __restrict__ fftHT,
    unsigned short* __restrict__ fftG) {
    __shared__ __align__(16) char smem[36864];
    short* As = (short*)smem;             // [128][72]
    short* Bs = (short*)(smem + 18432);   // [128][72]
    float* Ct = (float*)smem;             // epilogue reuse: [128][68]

    const int tid = threadIdx.x, lane = tid & 63, wave = tid >> 6;
    const int n0 = blockIdx.x * 128;  // 65 tiles, last partial
    const int m0 = blockIdx.y * 128;  // 16 tiles over 2048 rows
    floatx4 acc[2][8];
#pragma unroll
    for (int i = 0; i < 2; ++i)
#pragma unroll
        for (int j = 0; j < 8; ++j) acc[i][j] = (floatx4){0.f, 0.f, 0.f, 0.f};

    const int sr = tid >> 4, sc = (tid & 15) * 4;
    for (int kc = 0; kc < 4; ++kc) {
#pragma unroll
        for (int i = 0; i < 8; ++i) {
            const int row = sr + 16 * i;
            const int m = m0 + row;
            const float4 av = *(const float4*)(Whw + (size_t)(m >> 2) * MSZ + (m & 3) * 256 + kc * 64 + sc);
            *(ush4*)(&As[row * 72 + sc]) = pack4(av);
            const int n = n0 + row;
            ush4 bv;
            if (n < NSPEC) bv = *(const ush4*)(fftHT + (size_t)n * 256 + kc * 64 + sc);
            else { bv.x = bv.y = bv.z = bv.w = 0; }
            *(ush4*)(&Bs[row * 72 + sc]) = bv;
        }
        __syncthreads();
        const int arow = (wave * 32 + (lane & 15)) * 72;
        const int brow = (lane & 15) * 72;
        const int kq = 8 * (lane >> 4);
#pragma unroll
        for (int kk = 0; kk < 2; ++kk) {
            const int ko = kk * 32 + kq;
            const short8 a0 = *(const short8*)(&As[arow + ko]);
            const short8 a1 = *(const short8*)(&As[arow + 16 * 72 + ko]);
#pragma unroll
            for (int nf = 0; nf < 8; ++nf) {
                const short8 bv = *(const short8*)(&Bs[brow + nf * 16 * 72 + ko]);
                acc[0][nf] = __builtin_amdgcn_mfma_f32_16x16x32_bf16(a0, bv, acc[0][nf], 0, 0, 0);
                acc[1][nf] = __builtin_amdgcn_mfma_f32_16x16x32_bf16(a1, bv, acc[1][nf], 0, 0, 0);
            }
        }
        __syncthreads();
    }
    // epilogue: transpose C through LDS, pack bf16, 8B-coalesced stores
    const int wm = wave * 32;
#pragma unroll 1
    for (int half = 0; half < 2; ++half) {
        __syncthreads();
#pragma unroll
        for (int nfl = 0; nfl < 4; ++nfl) {
            const int nf = half * 4 + nfl;
            const int nloc = nfl * 16 + (lane & 15);
#pragma unroll
            for (int mf = 0; mf < 2; ++mf)
#pragma unroll
                for (int r = 0; r < 4; ++r) {
                    const int row = wm + mf * 16 + 4 * (lane >> 4) + r;
                    Ct[row * 68 + nloc] = acc[mf][nf][r];
                }
        }
        __syncthreads();
#pragma unroll
        for (int i = 0; i < 8; ++i) {
            const int idx = tid + i * 256;
            const int row = idx >> 4, f4 = idx & 15;
            const int n = n0 + half * 64 + f4 * 4;
            if (n < NSPEC) {
                const float4 v = *(const float4*)&Ct[row * 68 + f4 * 4];
                *(ush4*)&fftG[(size_t)(m0 + row) * NSPEC + n] = pack4(v);
            }
        }
    }
}

// ---------------- K5: S = sum_d fftU[b,d] * fftG[h,d]; y[b,h,:] = irfft(S)[0:4096] (bf16 out) ----------------
extern "C" __global__ __launch_bounds__(512) void conv_ifft_k(
    const float2* __restrict__ fftU, const unsigned short* __restrict__ fftG,
    unsigned short* __restrict__ y) {
    __shared__ float2 A[LDSN];
    __shared__ float2 S4096;
    const int h = blockIdx.x >> 3;
    const int b = blockIdx.x & 7;
    const int tid = threadIdx.x;
    const float2* U = fftU + (size_t)b * MD * FS;
    const unsigned short* G = fftG + (size_t)h * MD * NSPEC;
#pragma unroll
    for (int j = 0; j < 9; ++j) {
        const int k = tid + j * 512;
        if (k <= 4096) {
            float2 s = make_float2(0.f, 0.f);
#pragma unroll
            for (int d = 0; d < MD; ++d) {
                const float2 uu = U[d * FS + k];
                const unsigned gv = *(const unsigned*)(G + (size_t)d * NSPEC + 2 * k);
                const float gx = __uint_as_float(gv << 16);
                const float gy = __uint_as_float(gv & 0xFFFF0000u);
                s.x = fmaf(uu.x, gx, fmaf(-uu.y, gy, s.x));
                s.y = fmaf(uu.x, gy, fmaf(uu.y, gx, s.y));
            }
            if (k < 4096) A[PD(k)] = s;
            else S4096 = s;
        }
    }
    __syncthreads();
    float2 Sk[8], Sm[8];
#pragma unroll
    for (int j = 0; j < 8; ++j) {
        const int k = tid + j * 512;
        Sk[j] = A[PD(k)];
        Sm[j] = (k == 0) ? S4096 : A[PD(4096 - k)];
    }
    __syncthreads();
#pragma unroll
    for (int j = 0; j < 8; ++j) {
        const int k = tid + j * 512;
        const float2 E = make_float2(0.5f * (Sk[j].x + Sm[j].x), 0.5f * (Sk[j].y - Sm[j].y));
        const float2 D = make_float2(0.5f * (Sk[j].x - Sm[j].x), 0.5f * (Sk[j].y + Sm[j].y));
        float sn, cs;
        __sincosf(7.66990393942820614e-4f * (float)k, &sn, &cs);
        const float2 O = cmul(D, make_float2(cs, sn));
        A[PD(k)] = make_float2(E.x - O.y, E.y + O.x);
    }
    fft4096_ip<1>(A, tid);
    unsigned short* yp = y + (size_t)(b * HID + h) * LSEQ;
    const float inv = 1.0f / 4096.0f;
#pragma unroll
    for (int j = 0; j < 4; ++j) {
        const int n = tid + j * 512;
        const float2 z = A[PD(n)];
        const unsigned pk = (unsigned)f2bf(z.x * inv) | ((unsigned)f2bf(z.y * inv) << 16);
        *(unsigned*)(yp + 2 * n) = pk;  // x[2n], x[2n+1] as bf16 pair
    }
}

// ---------------- K6: h = relu(x @ Whw_x^T + y^T + bias) via bf16 MFMA; also h_last ----------------
extern "C" __global__ __launch_bounds__(256) void out_gemm_k(
    const float* __restrict__ x, const float* __restrict__ Whw, const float* __restrict__ Whb,
    const unsigned short* __restrict__ y, float* __restrict__ out) {
    __shared__ __align__(16) char smem[36864];
    short* As = (short*)smem;             // [128][72]
    short* Bs = (short*)(smem + 18432);   // [128][72]
    float* Ys = (float*)smem;             // epilogue: [64][132] (aliased, barrier-separated)
    float* Ct = (float*)smem;             // epilogue: [128][68]

    const int tid = threadIdx.x, lane = tid & 63, wave = tid >> 6;
    const int m0 = blockIdx.x * 128;
    const int h0 = blockIdx.y * 128;
    const int b = m0 >> 12;
    const int t0 = m0 & 4095;

    floatx4 acc[2][8];
#pragma unroll
    for (int i = 0; i < 2; ++i)
#pragma unroll
        for (int j = 0; j < 8; ++j) acc[i][j] = (floatx4){0.f, 0.f, 0.f, 0.f};

    const int sr = tid >> 4, sc = (tid & 15) * 4;
    const float* Axp = x + (size_t)(m0 + sr) * INS + sc;
    const float* Bxp = Whw + (size_t)(h0 + sr) * MSZ + 1024 + sc;

    for (int kc = 0; kc < 4; ++kc) {
#pragma unroll
        for (int i = 0; i < 8; ++i) {
            const int row = sr + 16 * i;
            const float4 av = *(const float4*)(Axp + (size_t)(16 * i) * INS + kc * 64);
            *(ush4*)(&As[row * 72 + sc]) = pack4(av);
            const float4 bv = *(const float4*)(Bxp + (size_t)(16 * i) * MSZ + kc * 64);
            *(ush4*)(&Bs[row * 72 + sc]) = pack4(bv);
        }
        __syncthreads();
        const int arow = (wave * 32 + (lane & 15)) * 72;
        const int brow = (lane & 15) * 72;
        const int kq = 8 * (lane >> 4);
#pragma unroll
        for (int kk = 0; kk < 2; ++kk) {
            const int ko = kk * 32 + kq;
            const short8 a0 = *(const short8*)(&As[arow + ko]);
            const short8 a1 = *(const short8*)(&As[arow + 16 * 72 + ko]);
#pragma unroll
            for (int nf = 0; nf < 8; ++nf) {
                const short8 bv = *(const short8*)(&Bs[brow + nf * 16 * 72 + ko]);
                acc[0][nf] = __builtin_amdgcn_mfma_f32_16x16x32_bf16(a0, bv, acc[0][nf], 0, 0, 0);
                acc[1][nf] = __builtin_amdgcn_mfma_f32_16x16x32_bf16(a1, bv, acc[1][nf], 0, 0, 0);
            }
        }
        __syncthreads();
    }

    // epilogue per 64-h half: stage y^T (bf16->fp32) -> relu(acc+y+bias) in regs
    // -> transpose via LDS -> float4 NT stores
    const int wm = wave * 32;
    const int yr = tid >> 5, yc = (tid & 31) * 4;
#pragma unroll 1
    for (int half = 0; half < 2; ++half) {
        __syncthreads();
#pragma unroll
        for (int i = 0; i < 8; ++i) {
            const int hh = yr + 8 * i;
            const ush4 v = *(const ush4*)(y + (size_t)(b * HID + h0 + half * 64 + hh) * LSEQ + t0 + yc);
            Ys[hh * 132 + yc + 0] = bf2f(v.x);
            Ys[hh * 132 + yc + 1] = bf2f(v.y);
            Ys[hh * 132 + yc + 2] = bf2f(v.z);
            Ys[hh * 132 + yc + 3] = bf2f(v.w);
        }
        __syncthreads();
        float v[4][2][4];
#pragma unroll
        for (int nfl = 0; nfl < 4; ++nfl) {
            const int nf = half * 4 + nfl;
            const int hh = nfl * 16 + (lane & 15);
            const float bias = Whb[h0 + half * 64 + hh];
#pragma unroll
            for (int mf = 0; mf < 2; ++mf)
#pragma unroll
                for (int r = 0; r < 4; ++r) {
                    const int row = wm + mf * 16 + 4 * (lane >> 4) + r;
                    v[nfl][mf][r] = fmaxf(acc[mf][nf][r] + Ys[hh * 132 + row] + bias, 0.f);
                }
        }
        __syncthreads();
#pragma unroll
        for (int nfl = 0; nfl < 4; ++nfl) {
            const int nloc = nfl * 16 + (lane & 15);
#pragma unroll
            for (int mf = 0; mf < 2; ++mf)
#pragma unroll
                for (int r = 0; r < 4; ++r) {
                    const int row = wm + mf * 16 + 4 * (lane >> 4) + r;
                    Ct[row * 68 + nloc] = v[nfl][mf][r];
                }
        }
        __syncthreads();
#pragma unroll
        for (int i = 0; i < 8; ++i) {
            const int idx = tid + i * 256;
            const int row = idx >> 4, f4 = idx & 15;
            const floatx4 t = *(const floatx4*)&Ct[row * 68 + f4 * 4];
            __builtin_nontemporal_store(t, (floatx4*)(out + (size_t)(m0 + row) * HID + h0 + half * 64 + f4 * 4));
            if (((m0 + row) & 4095) == 4095)
                __builtin_nontemporal_store(t, (floatx4*)(out + (size_t)NB * LSEQ * HID + (size_t)b * HID + h0 + half * 64 + f4 * 4));
        }
    }
}

extern "C" void kernel_launch(void* const* d_in, const int* in_sizes, int n_in,
                              void* d_out, int out_size, void* d_ws, size_t ws_size,
                              hipStream_t stream) {
    const float* x   = (const float*)d_in[0];
    const float* Wuw = (const float*)d_in[1];
    const float* Wub = (const float*)d_in[2];
    const float* Whw = (const float*)d_in[3];
    const float* Whb = (const float*)d_in[4];
    const float* H   = (const float*)d_in[5];
    char* wsb = (char*)d_ws;
    // workspace layout (bytes) — total ~73.2 MB
    unsigned short* fftG  = (unsigned short*)(wsb);             // 2048*8256 bf16   = 33,816,576
    unsigned short* yb    = (unsigned short*)(wsb + 33816576);  // 8*512*4096 bf16  = 33,554,432
    float*          fftU  = (float*)(wsb + 67371008);           // 32*4128*2 fp32   =  1,056,768
    unsigned short* fftHT = (unsigned short*)(wsb + 68427776);  // 8256*256 bf16    =  4,227,072
    float*          ut    = (float*)(wsb + 72654848);           // 32*4096 fp32     =    524,288
    float* out = (float*)d_out;

    hipLaunchKernelGGL(u_relu_k, dim3(8192), dim3(256), 0, stream, x, Wuw, Wub, ut);
    hipLaunchKernelGGL(rfft_u_k, dim3(32), dim3(512), 0, stream, ut, (float2*)fftU);
    hipLaunchKernelGGL(rfft_ht_k, dim3(256), dim3(512), 0, stream, H, fftHT);
    hipLaunchKernelGGL(g_gemm_k, dim3(65, 16), dim3(256), 0, stream, Whw, fftHT, fftG);
    hipLaunchKernelGGL(conv_ifft_k, dim3(4096), dim3(512), 0, stream,
                       (const float2*)fftU, fftG, yb);
    hipLaunchKernelGGL(out_gemm_k, dim3(256, 4), dim3(256), 0, stream, x, Whw, Whb, yb, out);
}

// Round 7
// 358.628 us; speedup vs baseline: 1.3193x; 1.2366x over previous
//
#include <hip/hip_runtime.h>

#define NB 8
#define LSEQ 4096
#define INS 256
#define MD 4
#define ORD 256
#define HID 512
#define MSZ 1280
#define FS 4128   // complex stride for spectrum rows (2*FS = 8256 floats)
#define NSPEC 8256

// padded LDS index for FFT kernels: +1 float2 per 8
#define PD(n) ((n) + ((n) >> 3))
#define LDSN 4608

typedef __attribute__((ext_vector_type(8))) short short8;
typedef __attribute__((ext_vector_type(4))) float floatx4;

struct ush4 { unsigned short x, y, z, w; };

__device__ __forceinline__ unsigned short f2bf(float f) {
    unsigned u = __float_as_uint(f);
    u += 0x7FFF + ((u >> 16) & 1);
    return (unsigned short)(u >> 16);
}
__device__ __forceinline__ ush4 pack4(float4 v) {
    ush4 p; p.x = f2bf(v.x); p.y = f2bf(v.y); p.z = f2bf(v.z); p.w = f2bf(v.w); return p;
}
__device__ __forceinline__ float bf2f(unsigned short s) {
    return __uint_as_float(((unsigned)s) << 16);
}

// ---------------- complex helpers ----------------
__device__ __forceinline__ float2 cmul(float2 a, float2 b) {
    return make_float2(fmaf(a.x, b.x, -(a.y * b.y)), fmaf(a.x, b.y, a.y * b.x));
}
__device__ __forceinline__ float2 cadd(float2 a, float2 b) { return make_float2(a.x + b.x, a.y + b.y); }
__device__ __forceinline__ float2 csub(float2 a, float2 b) { return make_float2(a.x - b.x, a.y - b.y); }

template <int DIR>
__device__ __forceinline__ float2 jmul(float2 z) {
    return (DIR < 0) ? make_float2(z.y, -z.x) : make_float2(-z.y, z.x);
}

// In-place Stockham DIF radix-8 stage on padded buffer. 512 threads.
template <int DIR, int N_, int S_>
__device__ __forceinline__ void fft_stage_ip(float2* __restrict__ X, int tid) {
    constexpr int M_ = N_ / 8;
    const int q = tid & (S_ - 1);
    const int p = tid / S_;
    const int rb = q + S_ * p;
    const float2 a0 = X[PD(rb + S_ * 0 * M_)];
    const float2 a1 = X[PD(rb + S_ * 1 * M_)];
    const float2 a2 = X[PD(rb + S_ * 2 * M_)];
    const float2 a3 = X[PD(rb + S_ * 3 * M_)];
    const float2 a4 = X[PD(rb + S_ * 4 * M_)];
    const float2 a5 = X[PD(rb + S_ * 5 * M_)];
    const float2 a6 = X[PD(rb + S_ * 6 * M_)];
    const float2 a7 = X[PD(rb + S_ * 7 * M_)];

    const float2 e0 = cadd(a0, a4), e1 = csub(a0, a4);
    const float2 e2 = cadd(a2, a6), e3 = jmul<DIR>(csub(a2, a6));
    const float2 E0 = cadd(e0, e2), E2 = csub(e0, e2);
    const float2 E1 = cadd(e1, e3), E3 = csub(e1, e3);
    const float2 f0 = cadd(a1, a5), f1 = csub(a1, a5);
    const float2 f2 = cadd(a3, a7), f3 = jmul<DIR>(csub(a3, a7));
    const float2 O0 = cadd(f0, f2), O2 = csub(f0, f2);
    const float2 O1 = cadd(f1, f3), O3 = csub(f1, f3);

    constexpr float C707 = 0.70710678118654752440f;
    const float2 W1 = make_float2(C707, DIR * C707);
    const float2 W3 = make_float2(-C707, DIR * C707);
    const float2 T1 = cmul(O1, W1);
    const float2 T2 = jmul<DIR>(O2);
    const float2 T3 = cmul(O3, W3);

    const float2 b0 = cadd(E0, O0), b4 = csub(E0, O0);
    const float2 b1 = cadd(E1, T1), b5 = csub(E1, T1);
    const float2 b2 = cadd(E2, T2), b6 = csub(E2, T2);
    const float2 b3 = cadd(E3, T3), b7 = csub(E3, T3);

    float sn, cs;
    __sincosf((DIR * 6.2831853071795864769f / (float)N_) * (float)p, &sn, &cs);
    const float2 w1 = make_float2(cs, sn);

    __syncthreads();

    const int wb = q + S_ * 8 * p;
    X[PD(wb + 0 * S_)] = b0;
    float2 w = w1;
    X[PD(wb + 1 * S_)] = cmul(b1, w); w = cmul(w, w1);
    X[PD(wb + 2 * S_)] = cmul(b2, w); w = cmul(w, w1);
    X[PD(wb + 3 * S_)] = cmul(b3, w); w = cmul(w, w1);
    X[PD(wb + 4 * S_)] = cmul(b4, w); w = cmul(w, w1);
    X[PD(wb + 5 * S_)] = cmul(b5, w); w = cmul(w, w1);
    X[PD(wb + 6 * S_)] = cmul(b6, w); w = cmul(w, w1);
    X[PD(wb + 7 * S_)] = cmul(b7, w);
    __syncthreads();
}

template <int DIR>
__device__ __forceinline__ void fft4096_ip(float2* A, int tid) {
    __syncthreads();
    fft_stage_ip<DIR, 4096, 1>(A, tid);
    fft_stage_ip<DIR, 512, 8>(A, tid);
    fft_stage_ip<DIR, 64, 64>(A, tid);
    fft_stage_ip<DIR, 8, 512>(A, tid);
}

// ---------------- K1: u = relu(x @ Wu_w^T + Wu_b) -> u_t[(b*4+d)][t]; also x_bf = bf16(x) ----------------
extern "C" __global__ __launch_bounds__(256) void u_relu_k(
    const float* __restrict__ x, const float* __restrict__ Wuw,
    const float* __restrict__ Wub, float* __restrict__ u_t,
    unsigned short* __restrict__ x_bf) {
    const int gid = blockIdx.x * 256 + threadIdx.x;
    const int row = gid >> 6;
    const int lane = threadIdx.x & 63;
    const float4 xv = ((const float4*)x)[(size_t)row * 64 + lane];
    *(ush4*)(&x_bf[(size_t)row * 256 + lane * 4]) = pack4(xv);
    const float4 w0 = ((const float4*)Wuw)[0 * 64 + lane];
    const float4 w1 = ((const float4*)Wuw)[1 * 64 + lane];
    const float4 w2 = ((const float4*)Wuw)[2 * 64 + lane];
    const float4 w3 = ((const float4*)Wuw)[3 * 64 + lane];
    float a0 = xv.x * w0.x + xv.y * w0.y + xv.z * w0.z + xv.w * w0.w;
    float a1 = xv.x * w1.x + xv.y * w1.y + xv.z * w1.z + xv.w * w1.w;
    float a2 = xv.x * w2.x + xv.y * w2.y + xv.z * w2.z + xv.w * w2.w;
    float a3 = xv.x * w3.x + xv.y * w3.y + xv.z * w3.z + xv.w * w3.w;
#pragma unroll
    for (int off = 1; off < 64; off <<= 1) {
        a0 += __shfl_xor(a0, off);
        a1 += __shfl_xor(a1, off);
        a2 += __shfl_xor(a2, off);
        a3 += __shfl_xor(a3, off);
    }
    if (lane < 4) {
        float v = (lane == 0) ? a0 : (lane == 1) ? a1 : (lane == 2) ? a2 : a3;
        v = fmaxf(v + Wub[lane], 0.0f);
        const int b = row >> 12, t = row & 4095;
        u_t[((size_t)(b * 4 + lane)) * LSEQ + t] = v;
    }
}

// ---------------- K1b: Whw fp32 -> bf16 ----------------
extern "C" __global__ __launch_bounds__(256) void wprep_k(
    const float* __restrict__ Whw, unsigned short* __restrict__ Whw_bf) {
    const int idx = blockIdx.x * 256 + threadIdx.x;  // 640 blocks: 163840 float4s
    const float4 v = ((const float4*)Whw)[idx];
    *(ush4*)(&Whw_bf[(size_t)idx * 4]) = pack4(v);
}

// ---------------- K2: fused rfft. blocks 0..31: u rows -> fftU fp32. blocks 32..287: H rows -> fftHB bf16 row-major ----------------
extern "C" __global__ __launch_bounds__(512) void rfft_all_k(
    const float* __restrict__ ut, const float* __restrict__ H,
    float2* __restrict__ fftU, unsigned short* __restrict__ fftHB) {
    __shared__ float2 A[LDSN];
    const int blk = blockIdx.x;
    const int tid = threadIdx.x;
    const bool is_u = (blk < 32);
    const float* src = is_u ? (ut + (size_t)blk * LSEQ) : (H + (size_t)(blk - 32) * LSEQ);
    const float2* rp = (const float2*)src;
#pragma unroll
    for (int j = 0; j < 8; ++j) {
        const int n = tid + j * 512;
        A[PD(n)] = (n < 2048) ? rp[n] : make_float2(0.f, 0.f);
    }
    fft4096_ip<-1>(A, tid);
    if (is_u) {
        float2* op = fftU + (size_t)blk * FS;
#pragma unroll
        for (int j = 0; j < 9; ++j) {
            const int k = tid + j * 512;
            if (k <= 4096) {
                const float2 Zk = A[PD(k & 4095)];
                const float2 Zm = A[PD((4096 - k) & 4095)];
                const float2 E = make_float2(0.5f * (Zk.x + Zm.x), 0.5f * (Zk.y - Zm.y));
                const float2 D = make_float2(0.5f * (Zk.x - Zm.x), 0.5f * (Zk.y + Zm.y));
                const float2 O = make_float2(D.y, -D.x);
                float sn, cs;
                __sincosf(-7.66990393942820614e-4f * (float)k, &sn, &cs);
                op[k] = cadd(E, cmul(make_float2(cs, sn), O));
            }
        }
    } else {
        const int o = blk - 32;
        unsigned* op = (unsigned*)(fftHB + (size_t)o * NSPEC);  // pair (2k,2k+1) per 4B
#pragma unroll
        for (int j = 0; j < 9; ++j) {
            const int k = tid + j * 512;
            if (k <= 4096) {
                const float2 Zk = A[PD(k & 4095)];
                const float2 Zm = A[PD((4096 - k) & 4095)];
                const float2 E = make_float2(0.5f * (Zk.x + Zm.x), 0.5f * (Zk.y - Zm.y));
                const float2 D = make_float2(0.5f * (Zk.x - Zm.x), 0.5f * (Zk.y + Zm.y));
                const float2 O = make_float2(D.y, -D.x);
                float sn, cs;
                __sincosf(-7.66990393942820614e-4f * (float)k, &sn, &cs);
                const float2 c = cadd(E, cmul(make_float2(cs, sn), O));
                if (2 * k < NSPEC)
                    op[k] = (unsigned)f2bf(c.x) | ((unsigned)f2bf(c.y) << 16);
            }
        }
    }
}

// ---------------- K2b: transpose fftHB [256 o][8256 s] bf16 -> fftHT [8256 s][256 o] bf16 (zero s>=8194) ----------------
extern "C" __global__ __launch_bounds__(256) void ht2_k(
    const unsigned short* __restrict__ fftHB, unsigned short* __restrict__ fftHT) {
    __shared__ unsigned short T[64 * 68];
    const int tid = threadIdx.x;
    const int s0 = blockIdx.x * 64;  // 129 blocks
    const int o0 = blockIdx.y * 64;  // 4 blocks
    const int r = tid >> 4, c4 = (tid & 15) * 4;
#pragma unroll
    for (int i = 0; i < 4; ++i) {
        const int o = r + 16 * i;
        const ush4 v = *(const ush4*)(fftHB + (size_t)(o0 + o) * NSPEC + s0 + c4);
        *(ush4*)(&T[o * 68 + c4]) = v;
    }
    __syncthreads();
#pragma unroll
    for (int i = 0; i < 4; ++i) {
        const int sl = r + 16 * i;
        const int s = s0 + sl;
        ush4 p;
        if (s < 8194) {
            p.x = T[(c4 + 0) * 68 + sl];
            p.y = T[(c4 + 1) * 68 + sl];
            p.z = T[(c4 + 2) * 68 + sl];
            p.w = T[(c4 + 3) * 68 + sl];
        } else { p.x = p.y = p.z = p.w = 0; }
        *(ush4*)(&fftHT[(size_t)s * 256 + o0 + c4]) = p;
    }
}

// ---------------- K4: fftG[m=h*4+d][n] = sum_o Whw_bf[h, d*256+o] * fftHT[n][o]  (bf16 MFMA, bf16 out) ----------------
extern "C" __global__ __launch_bounds__(256) void g_gemm_k(
    const unsigned short* __restrict__ Whw_bf, const unsigned short* __restrict__ fftHT,
    unsigned short* __restrict__ fftG) {
    __shared__ __align__(16) char smem[36864];
    short* As = (short*)smem;             // [128][72]
    short* Bs = (short*)(smem + 18432);   // [128][72]
    float* Ct = (float*)smem;             // epilogue reuse: [128][68]

    const int tid = threadIdx.x, lane = tid & 63, wave = tid >> 6;
    const int n0 = blockIdx.x * 128;  // 65 tiles, last partial
    const int m0 = blockIdx.y * 128;  // 16 tiles over 2048 rows
    floatx4 acc[2][8];
#pragma unroll
    for (int i = 0; i < 2; ++i)
#pragma unroll
        for (int j = 0; j < 8; ++j) acc[i][j] = (floatx4){0.f, 0.f, 0.f, 0.f};

    const int sr = tid >> 4, sc = (tid & 15) * 4;
    for (int kc = 0; kc < 4; ++kc) {
#pragma unroll
        for (int i = 0; i < 8; ++i) {
            const int row = sr + 16 * i;
            const int m = m0 + row;
            const ush4 av = *(const ush4*)(Whw_bf + (size_t)(m >> 2) * MSZ + (m & 3) * 256 + kc * 64 + sc);
            *(ush4*)(&As[row * 72 + sc]) = av;
            const int n = n0 + row;
            ush4 bv;
            if (n < NSPEC) bv = *(const ush4*)(fftHT + (size_t)n * 256 + kc * 64 + sc);
            else { bv.x = bv.y = bv.z = bv.w = 0; }
            *(ush4*)(&Bs[row * 72 + sc]) = bv;
        }
        __syncthreads();
        const int arow = (wave * 32 + (lane & 15)) * 72;
        const int brow = (lane & 15) * 72;
        const int kq = 8 * (lane >> 4);
#pragma unroll
        for (int kk = 0; kk < 2; ++kk) {
            const int ko = kk * 32 + kq;
            const short8 a0 = *(const short8*)(&As[arow + ko]);
            const short8 a1 = *(const short8*)(&As[arow + 16 * 72 + ko]);
#pragma unroll
            for (int nf = 0; nf < 8; ++nf) {
                const short8 bv = *(const short8*)(&Bs[brow + nf * 16 * 72 + ko]);
                acc[0][nf] = __builtin_amdgcn_mfma_f32_16x16x32_bf16(a0, bv, acc[0][nf], 0, 0, 0);
                acc[1][nf] = __builtin_amdgcn_mfma_f32_16x16x32_bf16(a1, bv, acc[1][nf], 0, 0, 0);
            }
        }
        __syncthreads();
    }
    // epilogue: transpose C through LDS, pack bf16, 8B-coalesced stores
    const int wm = wave * 32;
#pragma unroll 1
    for (int half = 0; half < 2; ++half) {
        __syncthreads();
#pragma unroll
        for (int nfl = 0; nfl < 4; ++nfl) {
            const int nf = half * 4 + nfl;
            const int nloc = nfl * 16 + (lane & 15);
#pragma unroll
            for (int mf = 0; mf < 2; ++mf)
#pragma unroll
                for (int r = 0; r < 4; ++r) {
                    const int row = wm + mf * 16 + 4 * (lane >> 4) + r;
                    Ct[row * 68 + nloc] = acc[mf][nf][r];
                }
        }
        __syncthreads();
#pragma unroll
        for (int i = 0; i < 8; ++i) {
            const int idx = tid + i * 256;
            const int row = idx >> 4, f4 = idx & 15;
            const int n = n0 + half * 64 + f4 * 4;
            if (n < NSPEC) {
                const float4 v = *(const float4*)&Ct[row * 68 + f4 * 4];
                *(ush4*)&fftG[(size_t)(m0 + row) * NSPEC + n] = pack4(v);
            }
        }
    }
}

// ---------------- K5: S = sum_d fftU[b,d] * fftG[h,d]; y[b,h,:] = irfft(S)[0:4096] (bf16 out) ----------------
extern "C" __global__ __launch_bounds__(512) void conv_ifft_k(
    const float2* __restrict__ fftU, const unsigned short* __restrict__ fftG,
    unsigned short* __restrict__ y) {
    __shared__ float2 A[LDSN];
    __shared__ float2 S4096;
    const int h = blockIdx.x >> 3;
    const int b = blockIdx.x & 7;
    const int tid = threadIdx.x;
    const float2* U = fftU + (size_t)b * MD * FS;
    const unsigned short* G = fftG + (size_t)h * MD * NSPEC;
#pragma unroll
    for (int j = 0; j < 9; ++j) {
        const int k = tid + j * 512;
        if (k <= 4096) {
            float2 s = make_float2(0.f, 0.f);
#pragma unroll
            for (int d = 0; d < MD; ++d) {
                const float2 uu = U[d * FS + k];
                const unsigned gv = *(const unsigned*)(G + (size_t)d * NSPEC + 2 * k);
                const float gx = __uint_as_float(gv << 16);
                const float gy = __uint_as_float(gv & 0xFFFF0000u);
                s.x = fmaf(uu.x, gx, fmaf(-uu.y, gy, s.x));
                s.y = fmaf(uu.x, gy, fmaf(uu.y, gx, s.y));
            }
            if (k < 4096) A[PD(k)] = s;
            else S4096 = s;
        }
    }
    __syncthreads();
    float2 Sk[8], Sm[8];
#pragma unroll
    for (int j = 0; j < 8; ++j) {
        const int k = tid + j * 512;
        Sk[j] = A[PD(k)];
        Sm[j] = (k == 0) ? S4096 : A[PD(4096 - k)];
    }
    __syncthreads();
#pragma unroll
    for (int j = 0; j < 8; ++j) {
        const int k = tid + j * 512;
        const float2 E = make_float2(0.5f * (Sk[j].x + Sm[j].x), 0.5f * (Sk[j].y - Sm[j].y));
        const float2 D = make_float2(0.5f * (Sk[j].x - Sm[j].x), 0.5f * (Sk[j].y + Sm[j].y));
        float sn, cs;
        __sincosf(7.66990393942820614e-4f * (float)k, &sn, &cs);
        const float2 O = cmul(D, make_float2(cs, sn));
        A[PD(k)] = make_float2(E.x - O.y, E.y + O.x);
    }
    fft4096_ip<1>(A, tid);
    unsigned short* yp = y + (size_t)(b * HID + h) * LSEQ;
    const float inv = 1.0f / 4096.0f;
#pragma unroll
    for (int j = 0; j < 4; ++j) {
        const int n = tid + j * 512;
        const float2 z = A[PD(n)];
        const unsigned pk = (unsigned)f2bf(z.x * inv) | ((unsigned)f2bf(z.y * inv) << 16);
        *(unsigned*)(yp + 2 * n) = pk;  // x[2n], x[2n+1] as bf16 pair
    }
}

// ---------------- K6: h = relu(x @ Whw_x^T + y^T + bias) via bf16 MFMA; also h_last ----------------
extern "C" __global__ __launch_bounds__(256) void out_gemm_k(
    const unsigned short* __restrict__ x_bf, const unsigned short* __restrict__ Whw_bf,
    const float* __restrict__ Whb, const unsigned short* __restrict__ y,
    float* __restrict__ out) {
    __shared__ __align__(16) char smem[36864];
    short* As = (short*)smem;             // [128][72]
    short* Bs = (short*)(smem + 18432);   // [128][72]
    float* Ys = (float*)smem;             // epilogue: [64][132] (aliased, barrier-separated)
    float* Ct = (float*)smem;             // epilogue: [128][68]

    const int tid = threadIdx.x, lane = tid & 63, wave = tid >> 6;
    const int m0 = blockIdx.x * 128;
    const int h0 = blockIdx.y * 128;
    const int b = m0 >> 12;
    const int t0 = m0 & 4095;

    floatx4 acc[2][8];
#pragma unroll
    for (int i = 0; i < 2; ++i)
#pragma unroll
        for (int j = 0; j < 8; ++j) acc[i][j] = (floatx4){0.f, 0.f, 0.f, 0.f};

    const int sr = tid >> 4, sc = (tid & 15) * 4;
    const unsigned short* Axp = x_bf + (size_t)(m0 + sr) * INS + sc;
    const unsigned short* Bxp = Whw_bf + (size_t)(h0 + sr) * MSZ + 1024 + sc;

    for (int kc = 0; kc < 4; ++kc) {
#pragma unroll
        for (int i = 0; i < 8; ++i) {
            const int row = sr + 16 * i;
            *(ush4*)(&As[row * 72 + sc]) = *(const ush4*)(Axp + (size_t)(16 * i) * INS + kc * 64);
            *(ush4*)(&Bs[row * 72 + sc]) = *(const ush4*)(Bxp + (size_t)(16 * i) * MSZ + kc * 64);
        }
        __syncthreads();
        const int arow = (wave * 32 + (lane & 15)) * 72;
        const int brow = (lane & 15) * 72;
        const int kq = 8 * (lane >> 4);
#pragma unroll
        for (int kk = 0; kk < 2; ++kk) {
            const int ko = kk * 32 + kq;
            const short8 a0 = *(const short8*)(&As[arow + ko]);
            const short8 a1 = *(const short8*)(&As[arow + 16 * 72 + ko]);
#pragma unroll
            for (int nf = 0; nf < 8; ++nf) {
                const short8 bv = *(const short8*)(&Bs[brow + nf * 16 * 72 + ko]);
                acc[0][nf] = __builtin_amdgcn_mfma_f32_16x16x32_bf16(a0, bv, acc[0][nf], 0, 0, 0);
                acc[1][nf] = __builtin_amdgcn_mfma_f32_16x16x32_bf16(a1, bv, acc[1][nf], 0, 0, 0);
            }
        }
        __syncthreads();
    }

    // epilogue per 64-h half: stage y^T (bf16->fp32) -> relu(acc+y+bias) in regs
    // -> transpose via LDS -> float4 NT stores
    const int wm = wave * 32;
    const int yr = tid >> 5, yc = (tid & 31) * 4;
#pragma unroll 1
    for (int half = 0; half < 2; ++half) {
        __syncthreads();
#pragma unroll
        for (int i = 0; i < 8; ++i) {
            const int hh = yr + 8 * i;
            const ush4 v = *(const ush4*)(y + (size_t)(b * HID + h0 + half * 64 + hh) * LSEQ + t0 + yc);
            Ys[hh * 132 + yc + 0] = bf2f(v.x);
            Ys[hh * 132 + yc + 1] = bf2f(v.y);
            Ys[hh * 132 + yc + 2] = bf2f(v.z);
            Ys[hh * 132 + yc + 3] = bf2f(v.w);
        }
        __syncthreads();
        float v[4][2][4];
#pragma unroll
        for (int nfl = 0; nfl < 4; ++nfl) {
            const int nf = half * 4 + nfl;
            const int hh = nfl * 16 + (lane & 15);
            const float bias = Whb[h0 + half * 64 + hh];
#pragma unroll
            for (int mf = 0; mf < 2; ++mf)
#pragma unroll
                for (int r = 0; r < 4; ++r) {
                    const int row = wm + mf * 16 + 4 * (lane >> 4) + r;
                    v[nfl][mf][r] = fmaxf(acc[mf][nf][r] + Ys[hh * 132 + row] + bias, 0.f);
                }
        }
        __syncthreads();
#pragma unroll
        for (int nfl = 0; nfl < 4; ++nfl) {
            const int nloc = nfl * 16 + (lane & 15);
#pragma unroll
            for (int mf = 0; mf < 2; ++mf)
#pragma unroll
                for (int r = 0; r < 4; ++r) {
                    const int row = wm + mf * 16 + 4 * (lane >> 4) + r;
                    Ct[row * 68 + nloc] = v[nfl][mf][r];
                }
        }
        __syncthreads();
#pragma unroll
        for (int i = 0; i < 8; ++i) {
            const int idx = tid + i * 256;
            const int row = idx >> 4, f4 = idx & 15;
            const floatx4 t = *(const floatx4*)&Ct[row * 68 + f4 * 4];
            __builtin_nontemporal_store(t, (floatx4*)(out + (size_t)(m0 + row) * HID + h0 + half * 64 + f4 * 4));
            if (((m0 + row) & 4095) == 4095)
                __builtin_nontemporal_store(t, (floatx4*)(out + (size_t)NB * LSEQ * HID + (size_t)b * HID + h0 + half * 64 + f4 * 4));
        }
    }
}

extern "C" void kernel_launch(void* const* d_in, const int* in_sizes, int n_in,
                              void* d_out, int out_size, void* d_ws, size_t ws_size,
                              hipStream_t stream) {
    const float* x   = (const float*)d_in[0];
    const float* Wuw = (const float*)d_in[1];
    const float* Wub = (const float*)d_in[2];
    const float* Whw = (const float*)d_in[3];
    const float* Whb = (const float*)d_in[4];
    const float* H   = (const float*)d_in[5];
    char* wsb = (char*)d_ws;
    // workspace layout (bytes) — total ~95.5 MB
    unsigned short* fftG   = (unsigned short*)(wsb);             // 2048*8256 bf16   = 33,816,576
    unsigned short* yb     = (unsigned short*)(wsb + 33816576);  // 8*512*4096 bf16  = 33,554,432
    float*          fftU   = (float*)(wsb + 67371008);           // 32*4128*2 fp32   =  1,056,768
    unsigned short* fftHT  = (unsigned short*)(wsb + 68427776);  // 8256*256 bf16    =  4,227,072
    float*          ut     = (float*)(wsb + 72654848);           // 32*4096 fp32     =    524,288
    unsigned short* x_bf   = (unsigned short*)(wsb + 73179136);  // 32768*256 bf16   = 16,777,216
    unsigned short* Whw_bf = (unsigned short*)(wsb + 89956352);  // 512*1280 bf16    =  1,310,720
    unsigned short* fftHB  = (unsigned short*)(wsb + 91267072);  // 256*8256 bf16    =  4,227,072
    float* out = (float*)d_out;

    hipLaunchKernelGGL(u_relu_k, dim3(8192), dim3(256), 0, stream, x, Wuw, Wub, ut, x_bf);
    hipLaunchKernelGGL(wprep_k, dim3(640), dim3(256), 0, stream, Whw, Whw_bf);
    hipLaunchKernelGGL(rfft_all_k, dim3(288), dim3(512), 0, stream, ut, H, (float2*)fftU, fftHB);
    hipLaunchKernelGGL(ht2_k, dim3(129, 4), dim3(256), 0, stream, fftHB, fftHT);
    hipLaunchKernelGGL(g_gemm_k, dim3(65, 16), dim3(256), 0, stream, Whw_bf, fftHT, fftG);
    hipLaunchKernelGGL(conv_ifft_k, dim3(4096), dim3(512), 0, stream,
                       (const float2*)fftU, fftG, yb);
    hipLaunchKernelGGL(out_gemm_k, dim3(256, 4), dim3(256), 0, stream, x_bf, Whw_bf, Whb, yb, out);
}